// Round 24
// baseline (376.705 us; speedup 1.0000x reference)
//
#include <hip/hip_runtime.h>
#include <math.h>

#define HH 128
#define WW 128
#define HWSZ 16384   // 128*128
#define CC 256
#define KK 64
#define BB 2

typedef __bf16 bf16x8_t __attribute__((ext_vector_type(8)));
typedef float  f32x4_t  __attribute__((ext_vector_type(4)));

__device__ __forceinline__ float silu_f(float v) { return v / (1.f + expf(-v)); }
__device__ __forceinline__ float sigm_f(float v) { return 1.f / (1.f + expf(-v)); }

__device__ __forceinline__ float b2f(unsigned short u) {
    union { unsigned int i; float f; } x; x.i = ((unsigned int)u) << 16; return x.f;
}
__device__ __forceinline__ unsigned short f2b(float f) {
    union { float f; unsigned int i; } x; x.f = f;
    unsigned int r = x.i + 0x7FFFu + ((x.i >> 16) & 1u);
    return (unsigned short)(r >> 16);
}
__device__ __forceinline__ float u2f(unsigned int u) {
    union { unsigned int i; float f; } x; x.i = u; return x.f;
}

// ---------------------------------------------------------------------------
// cvt body: l0 NCHW fp32 -> NHWC bf16 (block bid in [0,256)); bid 0 inits
// ymax/umax.
// ---------------------------------------------------------------------------
__device__ __forceinline__ void cvt_nhwc_body(int bid, float (*T)[128],
                                              const float* __restrict__ in,
                                              unsigned short* __restrict__ out,
                                              unsigned long long* __restrict__ ymax,
                                              unsigned int* __restrict__ umax) {
    const int tid = threadIdx.x;
    if (bid == 0) {
        if (tid < BB * KK) ymax[tid] = 0ull;
        if (tid >= 128 && tid < 128 + BB) umax[tid - 128] = 0u;
    }
    const int y = bid & 127;
    const int b = bid >> 7;
    const float* inb = in + (size_t)b * CC * HWSZ + y * 128;
    unsigned short* outb = out + ((size_t)b * HWSZ + (size_t)y * 128) * CC;

    for (int c0 = 0; c0 < CC; c0 += 32) {
        __syncthreads();
        {
            int cl = tid >> 3;
            int xq = tid & 7;
            const float4* src = (const float4*)(inb + (size_t)(c0 + cl) * HWSZ);
            float4* dst = (float4*)&T[cl][0];
            #pragma unroll
            for (int j = 0; j < 4; j++) dst[xq * 4 + j] = src[xq * 4 + j];
        }
        __syncthreads();
        {
            int x = tid & 127, ch = tid >> 7;
            union { unsigned short u[16]; uint4 v[2]; } pk;
            #pragma unroll
            for (int j = 0; j < 16; j++) pk.u[j] = f2b(T[ch * 16 + j][x]);
            uint4* dst = (uint4*)&outb[(size_t)x * CC + c0 + ch * 16];
            dst[0] = pk.v[0];
            dst[1] = pk.v[1];
        }
    }
}

// ---------------------------------------------------------------------------
// wprep body: one of 5 weight tensors, flattened block index L in [0, 11520).
// ---------------------------------------------------------------------------
#define WTSZ (9 * 8 * 256 * 32)
__device__ __forceinline__ void wprep_body(int L,
                                           const float* const* ws,
                                           unsigned short* __restrict__ wtbase) {
    int set = L / 2304;
    int blk = L - set * 2304;
    const float* w = ws[set];
    int idx = blk * 256 + threadIdx.x;
    int e   = idx & 7;
    int co  = (idx >> 3) & 255;
    int g   = (idx >> 11) & 3;
    int v   = idx >> 13;
    int cb  = v / 9;
    int t   = v - cb * 9;
    wtbase[(size_t)set * WTSZ + idx] = f2b(w[((size_t)co * 256 + cb * 32 + g * 8 + e) * 9 + t]);
}

// fused prep: blocks [0,256) cvt, [256, 256+11520) wprep
__global__ __launch_bounds__(256) void prep_fused_kernel(
    const float* __restrict__ l0, unsigned short* __restrict__ l0nh,
    unsigned long long* __restrict__ ymax, unsigned int* __restrict__ umax,
    const float* __restrict__ w0, const float* __restrict__ w1,
    const float* __restrict__ w2, const float* __restrict__ w3,
    const float* __restrict__ w4, unsigned short* __restrict__ wtbase)
{
    __shared__ float T[32][128];
    const int bid = blockIdx.x;
    if (bid < 256) {
        cvt_nhwc_body(bid, T, l0, l0nh, ymax, umax);
    } else {
        const float* ws[5] = {w0, w1, w2, w3, w4};
        wprep_body(bid - 256, ws, wtbase);
    }
}

// ---------------------------------------------------------------------------
// ycorr: y = s_e*s_t*relu(dot) + fused packed-argmax atomicMax.
// ---------------------------------------------------------------------------
#define EPAD 260
__global__ __launch_bounds__(256) void ycorr_kernel(const float* __restrict__ emb,
                                                    const float* __restrict__ trk,
                                                    float* __restrict__ y,
                                                    unsigned long long* __restrict__ ymax) {
    __shared__ __align__(16) float E[64 * EPAD];
    __shared__ __align__(16) float T[64 * EPAD];
    __shared__ float SE[64];
    __shared__ float ST[64];

    const int tid = threadIdx.x;
    const int b   = blockIdx.y;
    const int hw0 = blockIdx.x * 64;

    const float4* esrc = (const float4*)(emb + ((size_t)b * HWSZ + hw0) * CC);
    #pragma unroll
    for (int i = 0; i < 16; i++) {
        int q  = tid + i * 256;
        int px = q >> 6, c4 = q & 63;
        *(float4*)&E[px * EPAD + c4 * 4] = esrc[(size_t)px * 64 + c4];
    }
    const float4* tsrc = (const float4*)(trk + (size_t)b * KK * CC);
    #pragma unroll
    for (int i = 0; i < 16; i++) {
        int q = tid + i * 256;
        int k = q >> 6, c4 = q & 63;
        *(float4*)&T[k * EPAD + c4 * 4] = tsrc[(size_t)k * 64 + c4];
    }
    __syncthreads();

    if (tid < 64) {
        float ss = 0.f;
        const float4* ep = (const float4*)&E[tid * EPAD];
        #pragma unroll 8
        for (int c4 = 0; c4 < 64; c4++) {
            float4 v = ep[c4];
            ss += v.x * v.x + v.y * v.y + v.z * v.z + v.w * v.w;
        }
        SE[tid] = 1.f / fmaxf(sqrtf(ss), 1e-12f);
    } else if (tid < 128) {
        float ss = 0.f;
        const float4* tp = (const float4*)&T[(tid - 64) * EPAD];
        #pragma unroll 8
        for (int c4 = 0; c4 < 64; c4++) {
            float4 v = tp[c4];
            ss += v.x * v.x + v.y * v.y + v.z * v.z + v.w * v.w;
        }
        ST[tid - 64] = 1.f / fmaxf(sqrtf(ss), 1e-12f);
    }
    __syncthreads();

    const int pg = tid & 15;
    const int kg = tid >> 4;

    float acc[4][4];
    #pragma unroll
    for (int jp = 0; jp < 4; jp++)
        #pragma unroll
        for (int jk = 0; jk < 4; jk++) acc[jp][jk] = 0.f;

    const float* Ep[4];
    const float* Tp[4];
    #pragma unroll
    for (int jp = 0; jp < 4; jp++) Ep[jp] = &E[(jp * 16 + pg) * EPAD];
    #pragma unroll
    for (int jk = 0; jk < 4; jk++) Tp[jk] = &T[(jk * 16 + kg) * EPAD];

    #pragma unroll 2
    for (int c4 = 0; c4 < 64; ++c4) {
        float4 e[4], t[4];
        #pragma unroll
        for (int jp = 0; jp < 4; jp++) e[jp] = *(const float4*)(Ep[jp] + c4 * 4);
        #pragma unroll
        for (int jk = 0; jk < 4; jk++) t[jk] = *(const float4*)(Tp[jk] + c4 * 4);
        #define DOT4(a, t) (fmaf(a.w, t.w, fmaf(a.z, t.z, fmaf(a.y, t.y, a.x * t.x))))
        #pragma unroll
        for (int jp = 0; jp < 4; jp++)
            #pragma unroll
            for (int jk = 0; jk < 4; jk++)
                acc[jp][jk] += DOT4(e[jp], t[jk]);
        #undef DOT4
    }

    #pragma unroll
    for (int jk = 0; jk < 4; jk++) {
        int k = jk * 16 + kg;
        float st = ST[k];
        unsigned long long best = 0ull;
        #pragma unroll
        for (int jp = 0; jp < 4; jp++) {
            int px = jp * 16 + pg;
            float val = fmaxf(acc[jp][jk], 0.f) * SE[px] * st;
            y[((size_t)b * KK + k) * HWSZ + hw0 + px] = val;
            union { float f; unsigned int i; } u; u.f = val;
            unsigned long long pk =
                ((unsigned long long)u.i << 32) | (unsigned)(HWSZ - 1 - (hw0 + px));
            best = best > pk ? best : pk;
        }
        #pragma unroll
        for (int m = 1; m < 16; m <<= 1) {
            unsigned long long o = __shfl_xor(best, m);
            best = best > o ? best : o;
        }
        if (pg == 0) atomicMax(&ymax[b * KK + k], best);
    }
}

// ---------------------------------------------------------------------------
// smap body (bid in [0, 64*BB)); carves <2KB from smem.
// ---------------------------------------------------------------------------
__device__ __forceinline__ void smap_body(int bid, char* smem,
                                          const float* __restrict__ y,
                                          const unsigned long long* __restrict__ ymax,
                                          float* __restrict__ s,
                                          unsigned int* __restrict__ umax) {
    int* ai = (int*)smem;
    int* aj = (int*)(smem + 256);
    float* sm = (float*)(smem + 512);

    int b  = bid >> 6;
    int hw = (bid & 63) * 256 + threadIdx.x;
    int h  = hw >> 7, w = hw & 127;
    if (threadIdx.x < KK) {
        unsigned long long p = ymax[b * KK + threadIdx.x];
        int v = HWSZ - 1 - (int)(p & 0xFFFFFFFFull);
        ai[threadIdx.x] = v >> 7;
        aj[threadIdx.x] = v & 127;
    }
    __syncthreads();
    const float* yb = y + (size_t)b * KK * HWSZ;
    float acc = 0.f;
    #pragma unroll 8
    for (int k = 0; k < KK; k++) {
        float v = yb[(size_t)k * HWSZ + hw];
        bool in = (h >= ai[k] - 8) && (h < ai[k] + 8) && (w >= aj[k] - 8) && (w < aj[k] + 8);
        acc += in ? v : 0.f;
    }
    s[(size_t)b * HWSZ + hw] = acc;

    sm[threadIdx.x] = acc;
    __syncthreads();
    for (int st = 128; st > 0; st >>= 1) {
        if (threadIdx.x < st) sm[threadIdx.x] = fmaxf(sm[threadIdx.x], sm[threadIdx.x + st]);
        __syncthreads();
    }
    if (threadIdx.x == 0) {
        union { float f; unsigned int i; } x; x.f = sm[0];
        atomicMax(&umax[b], x.i);
    }
}

// ---------------------------------------------------------------------------
// deconv body (bid in [0, BB*CC)); carves 48KB from smem.
// ---------------------------------------------------------------------------
template <int HEADS>
__device__ __forceinline__ void deconv_body(int bid, char* smem,
                                            const float* __restrict__ l1,
                                            const float* __restrict__ l2,
                                            const float* __restrict__ w2a,
                                            const float* __restrict__ w3a,
                                            const float* __restrict__ w2b,
                                            const float* __restrict__ w3b,
                                            unsigned short* __restrict__ outA,
                                            unsigned short* __restrict__ outB) {
    float (*L1)[64][64] = (float (*)[64][64])smem;
    float (*L2)[32][32] = (float (*)[32][32])(smem + 32768);

    const int tid = threadIdx.x;
    const int g   = bid & 255;
    const int b   = bid >> 8;

    const float4* l1b = (const float4*)(l1 + ((size_t)b * 2 * CC + 2 * g) * 4096);
    float4* L1p = (float4*)&L1[0][0][0];
    #pragma unroll
    for (int i = 0; i < 8; i++) L1p[tid + i * 256] = l1b[tid + i * 256];
    const float4* l2b = (const float4*)(l2 + ((size_t)b * 4 * CC + 4 * g) * 1024);
    float4* L2p = (float4*)&L2[0][0][0];
    #pragma unroll
    for (int i = 0; i < 4; i++) L2p[tid + i * 256] = l2b[tid + i * 256];

    const int x    = tid & 127;
    const int ytop = tid >> 7;

    const int pxo = x & 1, pyo = ytop & 1;
    const int mx0 = (x + pxo - 2) >> 1;
    const int dy2 = (ytop + pyo - 2) >> 1;
    const bool nok0 = (unsigned)mx0 < 64u;
    const bool nok1 = (unsigned)(mx0 + 1) < 64u;
    const int nc0 = mx0 & 63, nc1 = (mx0 + 1) & 63;

    const int px3 = (5 - (x & 3)) & 3;
    const int n30 = (x + px3 - 5) >> 2;
    const bool n3ok0 = (unsigned)n30 < 32u;
    const bool n3ok1 = (unsigned)(n30 + 1) < 32u;
    const int n3c0 = n30 & 31, n3c1 = (n30 + 1) & 31;
    int dy3[2], py3v[2];
    #pragma unroll
    for (int ph = 0; ph < 2; ph++) {
        int py3 = (5 - ((ytop + 2 * ph) & 3)) & 3;
        py3v[ph] = py3;
        dy3[ph] = (2 * ph + ytop + py3 - 5) >> 2;
    }

    __syncthreads();

    const float* w2s[2] = {w2a, w2b};
    const float* w3s[2] = {w3a, w3b};
    unsigned short* outs[2] = {outA, outB};

    #pragma unroll 1
    for (int hd = 0; hd < HEADS; ++hd) {
        const float* w2g = w2s[hd] + (size_t)g * 32;
        const float* w3g = w3s[hd] + (size_t)g * 256;

        float W2[2][2][2];
        #pragma unroll
        for (int ci = 0; ci < 2; ci++)
            #pragma unroll
            for (int a = 0; a < 2; a++)
                #pragma unroll
                for (int c = 0; c < 2; c++)
                    W2[ci][a][c] = w2g[ci * 16 + (pyo + 2 * a) * 4 + (pxo + 2 * c)];
        float W3[2][4][2][2];
        #pragma unroll
        for (int ph = 0; ph < 2; ph++)
            #pragma unroll
            for (int ci = 0; ci < 4; ci++)
                #pragma unroll
                for (int a = 0; a < 2; a++)
                    #pragma unroll
                    for (int c = 0; c < 2; c++)
                        W3[ph][ci][a][c] = w3g[ci * 64 + (py3v[ph] + 4 * a) * 8 + (px3 + 4 * c)];

        unsigned short* outb = outs[hd] + ((size_t)b * CC + g) * HWSZ;

        #pragma unroll 2
        for (int ii = 0; ii < 32; ++ii) {
            #pragma unroll
            for (int ph = 0; ph < 2; ph++) {
                const int i = 2 * ii + ph;
                float acc = 0.f;
                {
                    const int m0 = i + dy2;
                    #pragma unroll
                    for (int a = 0; a < 2; a++) {
                        int m = m0 + a;
                        bool mok = (unsigned)m < 64u;
                        int mc = m & 63;
                        #pragma unroll
                        for (int ci = 0; ci < 2; ci++) {
                            float v0 = (mok && nok0) ? L1[ci][mc][nc0] : 0.f;
                            float v1 = (mok && nok1) ? L1[ci][mc][nc1] : 0.f;
                            acc = fmaf(W2[ci][a][0], v0, acc);
                            acc = fmaf(W2[ci][a][1], v1, acc);
                        }
                    }
                }
                {
                    const int m0 = ii + dy3[ph];
                    #pragma unroll
                    for (int a = 0; a < 2; a++) {
                        int m = m0 + a;
                        bool mok = (unsigned)m < 32u;
                        int mc = m & 31;
                        #pragma unroll
                        for (int ci = 0; ci < 4; ci++) {
                            float v0 = (mok && n3ok0) ? L2[ci][mc][n3c0] : 0.f;
                            float v1 = (mok && n3ok1) ? L2[ci][mc][n3c1] : 0.f;
                            acc = fmaf(W3[ph][ci][a][0], v0, acc);
                            acc = fmaf(W3[ph][ci][a][1], v1, acc);
                        }
                    }
                }
                outb[(size_t)i * 256 + tid] = f2b(acc);
            }
        }
    }
}

// standalone kernels (fallback path)
__global__ __launch_bounds__(256) void smap_kernel(const float* __restrict__ y,
                                                   const unsigned long long* __restrict__ ymax,
                                                   float* __restrict__ s,
                                                   unsigned int* __restrict__ umax) {
    __shared__ __align__(16) char smem[1536];
    smap_body(blockIdx.x, smem, y, ymax, s, umax);
}
template <int HEADS>
__global__ __launch_bounds__(256) void deconv_kernel(const float* __restrict__ l1,
                                                     const float* __restrict__ l2,
                                                     const float* __restrict__ w2a,
                                                     const float* __restrict__ w3a,
                                                     const float* __restrict__ w2b,
                                                     const float* __restrict__ w3b,
                                                     unsigned short* __restrict__ outA,
                                                     unsigned short* __restrict__ outB) {
    __shared__ __align__(16) char smem[49152];
    deconv_body<HEADS>(blockIdx.x, smem, l1, l2, w2a, w3a, w2b, w3b, outA, outB);
}

// fused smap || dual-deconv: blocks [0,128) smap, [128, 640) deconv
__global__ __launch_bounds__(256) void smapdeconv_kernel(
    const float* __restrict__ y, const unsigned long long* __restrict__ ymax,
    float* __restrict__ s, unsigned int* __restrict__ umax,
    const float* __restrict__ l1, const float* __restrict__ l2,
    const float* __restrict__ w2a, const float* __restrict__ w3a,
    const float* __restrict__ w2b, const float* __restrict__ w3b,
    unsigned short* __restrict__ outA, unsigned short* __restrict__ outB)
{
    __shared__ __align__(16) char smem[49152];
    const int bid = blockIdx.x;
    if (bid < 128) smap_body(bid, smem, y, ymax, s, umax);
    else           deconv_body<2>(bid - 128, smem, l1, l2, w2a, w3a, w2b, w3b, outA, outB);
}

// ---------------------------------------------------------------------------
// BIG conv core (round-15 dbuf body).
// ---------------------------------------------------------------------------
template <int ADDB, int MULF>
__device__ __forceinline__ void conv_mfma_body(
    int y0, int co0, int b,
    const unsigned short* __restrict__ in,
    const unsigned short* __restrict__ wt,
    const float* __restrict__ bias,
    const unsigned short* __restrict__ addb,
    const float* __restrict__ xf,
    unsigned short* __restrict__ out,
    unsigned short (*Alds)[3 * 130 * 32])
{
    const int tid  = threadIdx.x;
    const int lane = tid & 63;
    const int wv   = tid >> 6;
    const int wco  = wv >> 1;
    const int wpx  = wv & 1;
    const int l15  = lane & 15;
    const int kg   = lane >> 4;

    const unsigned short* inb = in + (size_t)b * HWSZ * CC;
    const float* xfb = MULF ? (xf + (size_t)b * HWSZ) : nullptr;
    const unsigned short* wp = wt + (size_t)kg * 2048 + (size_t)(co0 + wco * 64 + l15) * 8;

    int ach[3][4];
    #pragma unroll
    for (int tl = 0; tl < 3; tl++)
        #pragma unroll
        for (int f = 0; f < 4; f++) {
            int px = wpx * 64 + f * 16 + l15 + tl;
            ach[tl][f] = (px * 4 + (kg ^ ((px >> 1) & 3))) * 8;
        }

    f32x4_t acc[4][4];
    #pragma unroll
    for (int i = 0; i < 4; i++)
        #pragma unroll
        for (int j = 0; j < 4; j++)
            acc[i][j] = (f32x4_t){0.f, 0.f, 0.f, 0.f};

    if (tid < 48) {
        int q4 = tid & 3;
        int hp = (tid >> 2) & 1;
        int r  = (tid >> 3) % 3;
        int bi = tid / 24;
        int px = hp ? 129 : 0;
        int chunk = (r * 130 + px) * 4 + (q4 ^ ((px >> 1) & 3));
        *reinterpret_cast<uint4*>(&Alds[bi][chunk * 8]) = make_uint4(0u, 0u, 0u, 0u);
    }

    uint4 streg[6];
    float sxf[6];

    auto load_A = [&](int cb) {
        #pragma unroll
        for (int i = 0; i < 6; i++) {
            int q   = tid + i * 256;
            int q4  = q & 3;
            int pxi = (q >> 2) & 127;
            int r   = q >> 9;
            int gy  = y0 - 1 + r;
            uint4 v = make_uint4(0u, 0u, 0u, 0u);
            float fxv = 0.f;
            if ((unsigned)gy < 128u) {
                v = *reinterpret_cast<const uint4*>(
                        inb + ((size_t)(gy * 128 + pxi)) * CC + cb * 32 + q4 * 8);
                if (MULF) fxv = xfb[gy * 128 + pxi];
            }
            streg[i] = v;
            if (MULF) sxf[i] = fxv;
        }
    };
    auto write_A = [&](int bufi) {
        #pragma unroll
        for (int i = 0; i < 6; i++) {
            int q   = tid + i * 256;
            int q4  = q & 3;
            int pxi = (q >> 2) & 127;
            int r   = q >> 9;
            int px  = pxi + 1;
            int chunk = (r * 130 + px) * 4 + (q4 ^ ((px >> 1) & 3));
            uint4 v = streg[i];
            if (MULF) {
                union { unsigned short u[8]; uint4 w; } pk;
                pk.w = v;
                float fm = sxf[i];
                #pragma unroll
                for (int e = 0; e < 8; e++) pk.u[e] = f2b(b2f(pk.u[e]) * fm);
                v = pk.w;
            }
            *reinterpret_cast<uint4*>(&Alds[bufi][chunk * 8]) = v;
        }
    };

    load_A(0);
    write_A(0);

    bf16x8_t W[3][4], P[2][4];
    #pragma unroll
    for (int f = 0; f < 4; f++) W[0][f] = *reinterpret_cast<const bf16x8_t*>(wp + f * 128);
    #pragma unroll
    for (int f = 0; f < 4; f++) W[1][f] = *reinterpret_cast<const bf16x8_t*>(wp + 8192 + f * 128);

    __syncthreads();
    #pragma unroll
    for (int f = 0; f < 4; f++)
        P[0][f] = *reinterpret_cast<const bf16x8_t*>(&Alds[0][ach[0][f]]);

    for (int cb = 0; cb < 8; ++cb) {
        const int bufi = cb & 1;
        if (cb + 1 < 8) load_A(cb + 1);
        const unsigned short* wcb = wp + (size_t)cb * 73728;
        #pragma unroll
        for (int t = 0; t < 9; ++t) {
            if (cb < 7 || t < 7) {
                #pragma unroll
                for (int f = 0; f < 4; f++)
                    W[(t + 2) % 3][f] = *reinterpret_cast<const bf16x8_t*>(
                        wcb + (t + 2) * 8192 + f * 128);
            }
            if (t < 8) {
                const int aoff = ((t + 1) / 3) * 4160;
                #pragma unroll
                for (int f = 0; f < 4; f++)
                    P[(t + 1) & 1][f] = *reinterpret_cast<const bf16x8_t*>(
                        &Alds[bufi][aoff + ach[(t + 1) % 3][f]]);
            }
            __builtin_amdgcn_sched_barrier(0);
            #pragma unroll
            for (int cf = 0; cf < 4; cf++)
                #pragma unroll
                for (int pf = 0; pf < 4; pf++)
                    acc[cf][pf] = __builtin_amdgcn_mfma_f32_16x16x32_bf16(
                        W[t % 3][cf], P[t & 1][pf], acc[cf][pf], 0, 0, 0);
        }
        if (cb + 1 < 8) write_A(bufi ^ 1);
        __syncthreads();
        if (cb + 1 < 8) {
            #pragma unroll
            for (int f = 0; f < 4; f++)
                P[0][f] = *reinterpret_cast<const bf16x8_t*>(&Alds[(cb + 1) & 1][ach[0][f]]);
        }
    }

    size_t outB = ((size_t)b * HWSZ + (size_t)y0 * 128) * CC;
    #pragma unroll
    for (int cf = 0; cf < 4; cf++) {
        int co = co0 + wco * 64 + cf * 16 + kg * 4;
        float bs0 = bias[co], bs1 = bias[co + 1], bs2 = bias[co + 2], bs3 = bias[co + 3];
        #pragma unroll
        for (int pf = 0; pf < 4; pf++) {
            int x = wpx * 64 + pf * 16 + l15;
            float v0 = silu_f(acc[cf][pf][0] + bs0);
            float v1 = silu_f(acc[cf][pf][1] + bs1);
            float v2 = silu_f(acc[cf][pf][2] + bs2);
            float v3 = silu_f(acc[cf][pf][3] + bs3);
            if (ADDB) {
                size_t ab = ((size_t)b * CC + co) * HWSZ + (size_t)y0 * 128 + x;
                v0 += b2f(addb[ab]);
                v1 += b2f(addb[ab + HWSZ]);
                v2 += b2f(addb[ab + 2 * HWSZ]);
                v3 += b2f(addb[ab + 3 * HWSZ]);
            }
            union { unsigned short u[4]; uint2 v; } pk;
            pk.u[0] = f2b(v0); pk.u[1] = f2b(v1); pk.u[2] = f2b(v2); pk.u[3] = f2b(v3);
            *reinterpret_cast<uint2*>(&out[outB + (size_t)x * CC + co]) = pk.v;
        }
    }
}

// single-head conv (grid 512)
template <int ADDB, int MULF>
__global__ __launch_bounds__(256, 2) void conv_mfma_kernel(
    const unsigned short* __restrict__ in,
    const unsigned short* __restrict__ wt,
    const float* __restrict__ bias,
    const unsigned short* __restrict__ addb,
    const float* __restrict__ xf,
    unsigned short* __restrict__ out)
{
    __shared__ __align__(16) unsigned short Alds[2][3 * 130 * 32];
    const int l   = (blockIdx.x & 7) * 64 + (blockIdx.x >> 3);
    const int y0  = l >> 2;
    const int co0 = ((l >> 1) & 1) * 128;
    const int b   = l & 1;
    conv_mfma_body<ADDB, MULF>(y0, co0, b, in, wt, bias, addb, xf, out, Alds);
}

// dual-head p1 conv (grid 1024)
__global__ __launch_bounds__(256, 2) void conv_mfma_dual_kernel(
    const unsigned short* __restrict__ in,
    const unsigned short* __restrict__ wt2set,
    const float* __restrict__ biasB,
    const float* __restrict__ biasH,
    const unsigned short* __restrict__ addbB,
    const unsigned short* __restrict__ addbH,
    unsigned short* __restrict__ outB,
    unsigned short* __restrict__ outH)
{
    __shared__ __align__(16) unsigned short Alds[2][3 * 130 * 32];
    const int l    = (blockIdx.x & 7) * 128 + (blockIdx.x >> 3);
    const int y0   = l >> 3;
    const int c3   = l & 7;
    const int head = c3 >> 2;
    const int co0  = ((c3 >> 1) & 1) * 128;
    const int b    = c3 & 1;
    conv_mfma_body<1, 0>(y0, co0, b, in, wt2set + (size_t)head * WTSZ,
                         head ? biasH : biasB, head ? addbH : addbB,
                         nullptr, head ? outH : outB, Alds);
}

// dual-mix (grid 1024): head 0 = xb, head 1 = t2 (MULF)
__global__ __launch_bounds__(256, 2) void conv_mfma_dualmix_kernel(
    const unsigned short* __restrict__ in0,
    const unsigned short* __restrict__ in1,
    const unsigned short* __restrict__ wt0,
    const unsigned short* __restrict__ wt1,
    const float* __restrict__ bias0,
    const float* __restrict__ bias1,
    const float* __restrict__ xf,
    unsigned short* __restrict__ out0,
    unsigned short* __restrict__ out1)
{
    __shared__ __align__(16) unsigned short Alds[2][3 * 130 * 32];
    const int l    = (blockIdx.x & 7) * 128 + (blockIdx.x >> 3);
    const int y0   = l >> 3;
    const int c3   = l & 7;
    const int head = c3 >> 2;
    const int co0  = ((c3 >> 1) & 1) * 128;
    const int b    = c3 & 1;
    if (head == 0)
        conv_mfma_body<0, 0>(y0, co0, b, in0, wt0, bias0, nullptr, nullptr, out0, Alds);
    else
        conv_mfma_body<0, 1>(y0, co0, b, in1, wt1, bias1, nullptr, xf, out1, Alds);
}

// ---------------------------------------------------------------------------
// conv 1->256 (input = s / max), + bias, silu -> bf16 NHWC.
// ---------------------------------------------------------------------------
__global__ __launch_bounds__(256) void conv_c1a_kernel(const float* __restrict__ s,
                                                       const unsigned int* __restrict__ umax,
                                                       const float* __restrict__ w,
                                                       const float* __restrict__ bias,
                                                       unsigned short* __restrict__ out) {
    __shared__ float W[2304];
    __shared__ float S[3][34];

    const int tid = threadIdx.x;
    const int idx = blockIdx.x;
    const int b   = idx >> 9;
    const int seg = idx & 511;
    const int y   = seg >> 2;
    const int x0  = (seg & 3) * 32;

    for (int i = tid; i < 2304; i += 256) W[i] = w[i];
    if (tid < 102) {
        int r = tid / 34, xx = tid - r * 34;
        int gy = y - 1 + r, gx = x0 - 1 + xx;
        S[r][xx] = ((unsigned)gy < 128u && (unsigned)gx < 128u)
                       ? s[(size_t)b * HWSZ + gy * 128 + gx] : 0.f;
    }
    __syncthreads();

    const float im = 1.f / u2f(umax[b]);
    const int cog = tid >> 5;
    const int px  = tid & 31;

    float sv[9];
    #pragma unroll
    for (int r = 0; r < 3; r++)
        #pragma unroll
        for (int d = 0; d < 3; d++)
            sv[r * 3 + d] = S[r][px + d];

    unsigned short* op =
        &out[((size_t)b * HWSZ + (size_t)y * 128 + x0 + px) * CC + cog * 32];
    #pragma unroll
    for (int q = 0; q < 4; q++) {
        union { unsigned short u[8]; uint4 v; } pk;
        #pragma unroll
        for (int j = 0; j < 8; j++) {
            int co = cog * 32 + q * 8 + j;
            float a = 0.f;
            #pragma unroll
            for (int t = 0; t < 9; t++) a = fmaf(W[co * 9 + t], sv[t], a);
            pk.u[j] = f2b(silu_f(a * im + bias[co]));
        }
        *reinterpret_cast<uint4*>(op + q * 8) = pk.v;
    }
}

// ---------------------------------------------------------------------------
// Small conv body: 256 -> COUT, NHWC bf16 input; WL = smem float region.
// ---------------------------------------------------------------------------
template <int COUT, int MODE>
__device__ __forceinline__ void small_conv_body(int bid, float* WL,
                                                const unsigned short* __restrict__ in,
                                                const float* __restrict__ w,
                                                const float* __restrict__ bias,
                                                float* __restrict__ out)
{
    const int tid = threadIdx.x;
    for (int i = tid; i < COUT * 2304; i += 256) {
        int e = i & 7;
        int g = (i >> 3) & 31;
        int rest = i >> 8;
        int t = rest % 9;
        int co = rest / 9;
        WL[((co * 9 + t) * 32 + g) * 12 + e] = w[((size_t)co * 256 + g * 8 + e) * 9 + t];
    }
    __syncthreads();

    const int lane = tid & 63;
    const int wv   = tid >> 6;
    const int c32  = lane & 31;
    const int ps   = lane >> 5;
    const int grp  = bid * 4 + wv;
    const int base = grp * 4;
    const int b    = base >> 14;
    const int pix  = base & (HWSZ - 1);
    const int y    = pix >> 7;
    const int x0   = pix & 127;
    const int p0x  = x0 + 2 * ps;

    const unsigned short* inb = in + (size_t)b * HWSZ * CC;

    uint4 d[3][4];
    #pragma unroll
    for (int r = 0; r < 3; r++) {
        int gy = y - 1 + r;
        #pragma unroll
        for (int cx = 0; cx < 4; cx++) {
            int gx = p0x - 1 + cx;
            uint4 v = make_uint4(0u, 0u, 0u, 0u);
            if ((unsigned)gy < 128u && (unsigned)gx < 128u)
                v = *reinterpret_cast<const uint4*>(
                        inb + ((size_t)(gy * 128 + gx)) * CC + c32 * 8);
            d[r][cx] = v;
        }
    }

    float acc[2][COUT];
    #pragma unroll
    for (int p = 0; p < 2; p++)
        #pragma unroll
        for (int c = 0; c < COUT; c++) acc[p][c] = 0.f;

    #pragma unroll
    for (int r = 0; r < 3; r++) {
        float f[4][8];
        #pragma unroll
        for (int cx = 0; cx < 4; cx++) {
            union { unsigned short u[8]; uint4 v; } pk;
            pk.v = d[r][cx];
            #pragma unroll
            for (int e = 0; e < 8; e++) f[cx][e] = b2f(pk.u[e]);
        }
        #pragma unroll
        for (int dx = 0; dx < 3; dx++) {
            #pragma unroll
            for (int co = 0; co < COUT; co++) {
                int bse = ((co * 9 + r * 3 + dx) * 32 + c32) * 12;
                float4 wa = *(const float4*)&WL[bse];
                float4 wb = *(const float4*)&WL[bse + 4];
                #pragma unroll
                for (int p = 0; p < 2; p++) {
                    const float* ff = f[dx + p];
                    float a = acc[p][co];
                    a = fmaf(ff[0], wa.x, a); a = fmaf(ff[1], wa.y, a);
                    a = fmaf(ff[2], wa.z, a); a = fmaf(ff[3], wa.w, a);
                    a = fmaf(ff[4], wb.x, a); a = fmaf(ff[5], wb.y, a);
                    a = fmaf(ff[6], wb.z, a); a = fmaf(ff[7], wb.w, a);
                    acc[p][co] = a;
                }
            }
        }
    }

    #pragma unroll
    for (int m = 1; m <= 16; m <<= 1)
        #pragma unroll
        for (int p = 0; p < 2; p++)
            #pragma unroll
            for (int co = 0; co < COUT; co++)
                acc[p][co] += __shfl_xor(acc[p][co], m);

    if (c32 == 0) {
        #pragma unroll
        for (int p = 0; p < 2; p++) {
            size_t pixidx = (size_t)base + 2 * ps + p;
            if (MODE == 0) {
                ((float4*)out)[pixidx] = make_float4(
                    acc[p][0] + bias[0],
                    acc[p][COUT > 1 ? 1 : 0] + bias[COUT > 1 ? 1 : 0],
                    acc[p][COUT > 2 ? 2 : 0] + bias[COUT > 2 ? 2 : 0],
                    acc[p][COUT > 3 ? 3 : 0] + bias[COUT > 3 ? 3 : 0]);
            } else if (MODE == 1) {
                out[pixidx] = acc[p][0] + bias[0];
            } else {
                out[pixidx] = sigm_f(acc[p][0] + bias[0]);
            }
        }
    }
}

template <int COUT, int MODE>
__global__ __launch_bounds__(256) void small_conv_kernel(
    const unsigned short* __restrict__ in,
    const float* __restrict__ w,
    const float* __restrict__ bias,
    float* __restrict__ out)
{
    __shared__ float WL[COUT * 9 * 32 * 12];
    small_conv_body<COUT, MODE>(blockIdx.x, WL, in, w, bias, out);
}

// fused t3 || c2box: blocks [0,512) t3 conv, [512, 2560) small_conv<4,0>
__global__ __launch_bounds__(256, 2) void t3c2_kernel(
    const unsigned short* __restrict__ t2in,     // bufA
    const unsigned short* __restrict__ wt4,      // h_c2b set
    const float* __restrict__ biasT3,
    unsigned short* __restrict__ t3out,          // bufB
    const unsigned short* __restrict__ xbin,     // bufD
    const float* __restrict__ c2w,
    const float* __restrict__ c2b,
    float* __restrict__ boxout)
{
    __shared__ __align__(16) char smem[55296];
    const int bid = blockIdx.x;
    if (bid < 512) {
        const int l   = (bid & 7) * 64 + (bid >> 3);
        const int y0  = l >> 2;
        const int co0 = ((l >> 1) & 1) * 128;
        const int b   = l & 1;
        conv_mfma_body<0, 0>(y0, co0, b, t2in, wt4, biasT3, nullptr, nullptr, t3out,
                             (unsigned short (*)[3 * 130 * 32])smem);
    } else {
        small_conv_body<4, 0>(bid - 512, (float*)smem, xbin, c2w, c2b, boxout);
    }
}

// ---------------------------------------------------------------------------
extern "C" void kernel_launch(void* const* d_in, const int* in_sizes, int n_in,
                              void* d_out, int out_size, void* d_ws, size_t ws_size,
                              hipStream_t stream) {
    const float* emb    = (const float*)d_in[0];
    const float* trk    = (const float*)d_in[1];
    const float* l0     = (const float*)d_in[2];
    const float* l1     = (const float*)d_in[3];
    const float* l2     = (const float*)d_in[4];
    const float* b_p1w  = (const float*)d_in[5];
    const float* b_p1b  = (const float*)d_in[6];
    const float* b_p2w  = (const float*)d_in[7];
    const float* b_p3w  = (const float*)d_in[8];
    const float* b_c1w  = (const float*)d_in[9];
    const float* b_c1b  = (const float*)d_in[10];
    const float* b_c2w  = (const float*)d_in[11];
    const float* b_c2b  = (const float*)d_in[12];
    const float* h_p1w  = (const float*)d_in[13];
    const float* h_p1b  = (const float*)d_in[14];
    const float* h_p2w  = (const float*)d_in[15];
    const float* h_p3w  = (const float*)d_in[16];
    const float* h_c1aw = (const float*)d_in[17];
    const float* h_c1ab = (const float*)d_in[18];
    const float* h_c1bw = (const float*)d_in[19];
    const float* h_c1bb = (const float*)d_in[20];
    const float* h_c2aw = (const float*)d_in[21];
    const float* h_c2ab = (const float*)d_in[22];
    const float* h_c2bw = (const float*)d_in[23];
    const float* h_c2bb = (const float*)d_in[24];
    const float* h_c2cw = (const float*)d_in[25];
    const float* h_c2cb = (const float*)d_in[26];

    float* outp = (float*)d_out;   // [0,32768): hmmap ; [32768,163840): siambox NHWC

    const size_t ACT = (size_t)BB * CC * HWSZ;   // 8,388,608 elems
    const size_t WT  = (size_t)WTSZ;             // 589,824 elems
    const size_t SMALLS = 132096;                // ushort units for small fp32 region

    unsigned short* l0nh = (unsigned short*)d_ws;
    unsigned short* wtP  = l0nh + ACT;           // set0=b_p1, 1=h_p1, 2=b_c1, 3=h_c2a, 4=h_c2b
    unsigned short* bufA = wtP + 5 * WT;
    unsigned short* bufB = bufA + ACT;
    unsigned short* bufC = bufB + ACT;
    float* sbuf   = (float*)(bufC + ACT);
    float* xfb    = sbuf + (size_t)BB * HWSZ;
    unsigned long long* ymax = (unsigned long long*)(xfb + (size_t)BB * HWSZ);
    unsigned int* umax = (unsigned int*)(ymax + BB * KK);
    unsigned short* bufD = bufC + ACT + SMALLS;  // fast-path only
    float* ybuf   = (float*)bufB;                // alias: y consumed before bufB reused

    const size_t NEED = (size_t)(bufD + ACT - l0nh) * sizeof(unsigned short);
    const bool fast = ws_size >= NEED;

    // L1: fused preps (cvt + 5x wprep); cvt block 0 inits ymax/umax
    prep_fused_kernel<<<256 + 11520, 256, 0, stream>>>(
        l0, l0nh, ymax, umax, b_p1w, h_p1w, b_c1w, h_c2aw, h_c2bw, wtP);

    // L2: correlation + fused argmax
    ycorr_kernel<<<dim3(256, BB), 256, 0, stream>>>(emb, trk, ybuf, ymax);

    if (fast) {
        // L3: smap || dual deconv (box->bufA, hm->bufD)
        smapdeconv_kernel<<<128 + 512, 256, 0, stream>>>(
            ybuf, ymax, sbuf, umax,
            l1, l2, b_p2w, b_p3w, h_p2w, h_p3w, bufA, bufD);
        // L4: t1 -> bufB
        conv_c1a_kernel<<<1024, 256, 0, stream>>>(sbuf, umax, h_c1aw, h_c1ab, bufB);
        // L5: xf (bufB -> xfb)
        small_conv_kernel<1, 1><<<2048, 256, 0, stream>>>(bufB, h_c1bw, h_c1bb, xfb);
        // L6: dual p1: xd_box->bufB, xd_hm->bufC
        conv_mfma_dual_kernel<<<1024, 256, 0, stream>>>(l0nh, wtP, b_p1b, h_p1b,
                                                        bufA, bufD, bufB, bufC);
        // L7: dual mix: xb (bufB->bufD) || t2 (bufC * xf -> bufA)
        conv_mfma_dualmix_kernel<<<1024, 256, 0, stream>>>(bufB, bufC,
                                                           wtP + 2 * WT, wtP + 3 * WT,
                                                           b_c1b, h_c2ab, xfb,
                                                           bufD, bufA);
        // L8: t3 (bufA->bufB) || c2box (bufD->out)
        t3c2_kernel<<<512 + 2048, 256, 0, stream>>>(bufA, wtP + 4 * WT, h_c2bb, bufB,
                                                    bufD, b_c2w, b_c2b,
                                                    outp + BB * HWSZ);
        // L9: hmmap (bufB -> out)
        small_conv_kernel<1, 2><<<2048, 256, 0, stream>>>(bufB, h_c2cw, h_c2cb, outp);
    } else {
        // fallback schedule (Db=bufA, X1=bufB, X2=bufC), all singles
        smap_kernel<<<64 * BB, 256, 0, stream>>>(ybuf, ymax, sbuf, umax);
        deconv_kernel<1><<<BB * CC, 256, 0, stream>>>(l1, l2, b_p2w, b_p3w,
                                                      nullptr, nullptr, bufA, nullptr);
        conv_mfma_kernel<1, 0><<<512, 256, 0, stream>>>(l0nh, wtP, b_p1b, bufA,
                                                        nullptr, bufB);                 // xd_box
        conv_mfma_kernel<0, 0><<<512, 256, 0, stream>>>(bufB, wtP + 2 * WT, b_c1b,
                                                        nullptr, nullptr, bufC);        // xb
        small_conv_kernel<4, 0><<<2048, 256, 0, stream>>>(bufC, b_c2w, b_c2b,
                                                          outp + BB * HWSZ);
        deconv_kernel<1><<<BB * CC, 256, 0, stream>>>(l1, l2, h_p2w, h_p3w,
                                                      nullptr, nullptr, bufA, nullptr);
        conv_mfma_kernel<1, 0><<<512, 256, 0, stream>>>(l0nh, wtP + 1 * WT, h_p1b, bufA,
                                                        nullptr, bufB);                 // xd_hm
        conv_c1a_kernel<<<1024, 256, 0, stream>>>(sbuf, umax, h_c1aw, h_c1ab, bufC);    // t1
        small_conv_kernel<1, 1><<<2048, 256, 0, stream>>>(bufC, h_c1bw, h_c1bb, xfb);   // xf
        conv_mfma_kernel<0, 1><<<512, 256, 0, stream>>>(bufB, wtP + 3 * WT, h_c2ab,
                                                        nullptr, xfb, bufA);            // t2
        conv_mfma_kernel<0, 0><<<512, 256, 0, stream>>>(bufA, wtP + 4 * WT, h_c2bb,
                                                        nullptr, nullptr, bufC);        // t3
        small_conv_kernel<1, 2><<<2048, 256, 0, stream>>>(bufC, h_c2cw, h_c2cb, outp);  // hmmap
    }
}

// Round 25
// 369.605 us; speedup vs baseline: 1.0192x; 1.0192x over previous
//
#include <hip/hip_runtime.h>
#include <math.h>

#define HH 128
#define WW 128
#define HWSZ 16384   // 128*128
#define CC 256
#define KK 64
#define BB 2

typedef __bf16 bf16x8_t __attribute__((ext_vector_type(8)));
typedef float  f32x4_t  __attribute__((ext_vector_type(4)));

__device__ __forceinline__ float silu_f(float v) { return v / (1.f + expf(-v)); }
__device__ __forceinline__ float sigm_f(float v) { return 1.f / (1.f + expf(-v)); }

__device__ __forceinline__ float b2f(unsigned short u) {
    union { unsigned int i; float f; } x; x.i = ((unsigned int)u) << 16; return x.f;
}
__device__ __forceinline__ unsigned short f2b(float f) {
    union { float f; unsigned int i; } x; x.f = f;
    unsigned int r = x.i + 0x7FFFu + ((x.i >> 16) & 1u);
    return (unsigned short)(r >> 16);
}
__device__ __forceinline__ float u2f(unsigned int u) {
    union { unsigned int i; float f; } x; x.i = u; return x.f;
}

// ---------------------------------------------------------------------------
// cvt body: l0 NCHW fp32 -> NHWC bf16 (block bid in [0,256)); bid 0 inits
// ymax/umax.
// ---------------------------------------------------------------------------
__device__ __forceinline__ void cvt_nhwc_body(int bid, float (*T)[128],
                                              const float* __restrict__ in,
                                              unsigned short* __restrict__ out,
                                              unsigned long long* __restrict__ ymax,
                                              unsigned int* __restrict__ umax) {
    const int tid = threadIdx.x;
    if (bid == 0) {
        if (tid < BB * KK) ymax[tid] = 0ull;
        if (tid >= 128 && tid < 128 + BB) umax[tid - 128] = 0u;
    }
    const int y = bid & 127;
    const int b = bid >> 7;
    const float* inb = in + (size_t)b * CC * HWSZ + y * 128;
    unsigned short* outb = out + ((size_t)b * HWSZ + (size_t)y * 128) * CC;

    for (int c0 = 0; c0 < CC; c0 += 32) {
        __syncthreads();
        {
            int cl = tid >> 3;
            int xq = tid & 7;
            const float4* src = (const float4*)(inb + (size_t)(c0 + cl) * HWSZ);
            float4* dst = (float4*)&T[cl][0];
            #pragma unroll
            for (int j = 0; j < 4; j++) dst[xq * 4 + j] = src[xq * 4 + j];
        }
        __syncthreads();
        {
            int x = tid & 127, ch = tid >> 7;
            union { unsigned short u[16]; uint4 v[2]; } pk;
            #pragma unroll
            for (int j = 0; j < 16; j++) pk.u[j] = f2b(T[ch * 16 + j][x]);
            uint4* dst = (uint4*)&outb[(size_t)x * CC + c0 + ch * 16];
            dst[0] = pk.v[0];
            dst[1] = pk.v[1];
        }
    }
}

// ---------------------------------------------------------------------------
// wprep body: one of 5 weight tensors, flattened block index L in [0, 11520).
// ---------------------------------------------------------------------------
#define WTSZ (9 * 8 * 256 * 32)
__device__ __forceinline__ void wprep_body(int L,
                                           const float* const* ws,
                                           unsigned short* __restrict__ wtbase) {
    int set = L / 2304;
    int blk = L - set * 2304;
    const float* w = ws[set];
    int idx = blk * 256 + threadIdx.x;
    int e   = idx & 7;
    int co  = (idx >> 3) & 255;
    int g   = (idx >> 11) & 3;
    int v   = idx >> 13;
    int cb  = v / 9;
    int t   = v - cb * 9;
    wtbase[(size_t)set * WTSZ + idx] = f2b(w[((size_t)co * 256 + cb * 32 + g * 8 + e) * 9 + t]);
}

// fused prep: blocks [0,256) cvt, [256, 256+11520) wprep
__global__ __launch_bounds__(256) void prep_fused_kernel(
    const float* __restrict__ l0, unsigned short* __restrict__ l0nh,
    unsigned long long* __restrict__ ymax, unsigned int* __restrict__ umax,
    const float* __restrict__ w0, const float* __restrict__ w1,
    const float* __restrict__ w2, const float* __restrict__ w3,
    const float* __restrict__ w4, unsigned short* __restrict__ wtbase)
{
    __shared__ float T[32][128];
    const int bid = blockIdx.x;
    if (bid < 256) {
        cvt_nhwc_body(bid, T, l0, l0nh, ymax, umax);
    } else {
        const float* ws[5] = {w0, w1, w2, w3, w4};
        wprep_body(bid - 256, ws, wtbase);
    }
}

// ---------------------------------------------------------------------------
// ycorr: y = s_e*s_t*relu(dot) + fused packed-argmax atomicMax.
// ---------------------------------------------------------------------------
#define EPAD 260
__global__ __launch_bounds__(256) void ycorr_kernel(const float* __restrict__ emb,
                                                    const float* __restrict__ trk,
                                                    float* __restrict__ y,
                                                    unsigned long long* __restrict__ ymax) {
    __shared__ __align__(16) float E[64 * EPAD];
    __shared__ __align__(16) float T[64 * EPAD];
    __shared__ float SE[64];
    __shared__ float ST[64];

    const int tid = threadIdx.x;
    const int b   = blockIdx.y;
    const int hw0 = blockIdx.x * 64;

    const float4* esrc = (const float4*)(emb + ((size_t)b * HWSZ + hw0) * CC);
    #pragma unroll
    for (int i = 0; i < 16; i++) {
        int q  = tid + i * 256;
        int px = q >> 6, c4 = q & 63;
        *(float4*)&E[px * EPAD + c4 * 4] = esrc[(size_t)px * 64 + c4];
    }
    const float4* tsrc = (const float4*)(trk + (size_t)b * KK * CC);
    #pragma unroll
    for (int i = 0; i < 16; i++) {
        int q = tid + i * 256;
        int k = q >> 6, c4 = q & 63;
        *(float4*)&T[k * EPAD + c4 * 4] = tsrc[(size_t)k * 64 + c4];
    }
    __syncthreads();

    if (tid < 64) {
        float ss = 0.f;
        const float4* ep = (const float4*)&E[tid * EPAD];
        #pragma unroll 8
        for (int c4 = 0; c4 < 64; c4++) {
            float4 v = ep[c4];
            ss += v.x * v.x + v.y * v.y + v.z * v.z + v.w * v.w;
        }
        SE[tid] = 1.f / fmaxf(sqrtf(ss), 1e-12f);
    } else if (tid < 128) {
        float ss = 0.f;
        const float4* tp = (const float4*)&T[(tid - 64) * EPAD];
        #pragma unroll 8
        for (int c4 = 0; c4 < 64; c4++) {
            float4 v = tp[c4];
            ss += v.x * v.x + v.y * v.y + v.z * v.z + v.w * v.w;
        }
        ST[tid - 64] = 1.f / fmaxf(sqrtf(ss), 1e-12f);
    }
    __syncthreads();

    const int pg = tid & 15;
    const int kg = tid >> 4;

    float acc[4][4];
    #pragma unroll
    for (int jp = 0; jp < 4; jp++)
        #pragma unroll
        for (int jk = 0; jk < 4; jk++) acc[jp][jk] = 0.f;

    const float* Ep[4];
    const float* Tp[4];
    #pragma unroll
    for (int jp = 0; jp < 4; jp++) Ep[jp] = &E[(jp * 16 + pg) * EPAD];
    #pragma unroll
    for (int jk = 0; jk < 4; jk++) Tp[jk] = &T[(jk * 16 + kg) * EPAD];

    #pragma unroll 2
    for (int c4 = 0; c4 < 64; ++c4) {
        float4 e[4], t[4];
        #pragma unroll
        for (int jp = 0; jp < 4; jp++) e[jp] = *(const float4*)(Ep[jp] + c4 * 4);
        #pragma unroll
        for (int jk = 0; jk < 4; jk++) t[jk] = *(const float4*)(Tp[jk] + c4 * 4);
        #define DOT4(a, t) (fmaf(a.w, t.w, fmaf(a.z, t.z, fmaf(a.y, t.y, a.x * t.x))))
        #pragma unroll
        for (int jp = 0; jp < 4; jp++)
            #pragma unroll
            for (int jk = 0; jk < 4; jk++)
                acc[jp][jk] += DOT4(e[jp], t[jk]);
        #undef DOT4
    }

    #pragma unroll
    for (int jk = 0; jk < 4; jk++) {
        int k = jk * 16 + kg;
        float st = ST[k];
        unsigned long long best = 0ull;
        #pragma unroll
        for (int jp = 0; jp < 4; jp++) {
            int px = jp * 16 + pg;
            float val = fmaxf(acc[jp][jk], 0.f) * SE[px] * st;
            y[((size_t)b * KK + k) * HWSZ + hw0 + px] = val;
            union { float f; unsigned int i; } u; u.f = val;
            unsigned long long pk =
                ((unsigned long long)u.i << 32) | (unsigned)(HWSZ - 1 - (hw0 + px));
            best = best > pk ? best : pk;
        }
        #pragma unroll
        for (int m = 1; m < 16; m <<= 1) {
            unsigned long long o = __shfl_xor(best, m);
            best = best > o ? best : o;
        }
        if (pg == 0) atomicMax(&ymax[b * KK + k], best);
    }
}

// ---------------------------------------------------------------------------
// smap body (bid in [0, 64*BB)); carves <2KB from smem.
// ---------------------------------------------------------------------------
__device__ __forceinline__ void smap_body(int bid, char* smem,
                                          const float* __restrict__ y,
                                          const unsigned long long* __restrict__ ymax,
                                          float* __restrict__ s,
                                          unsigned int* __restrict__ umax) {
    int* ai = (int*)smem;
    int* aj = (int*)(smem + 256);
    float* sm = (float*)(smem + 512);

    int b  = bid >> 6;
    int hw = (bid & 63) * 256 + threadIdx.x;
    int h  = hw >> 7, w = hw & 127;
    if (threadIdx.x < KK) {
        unsigned long long p = ymax[b * KK + threadIdx.x];
        int v = HWSZ - 1 - (int)(p & 0xFFFFFFFFull);
        ai[threadIdx.x] = v >> 7;
        aj[threadIdx.x] = v & 127;
    }
    __syncthreads();
    const float* yb = y + (size_t)b * KK * HWSZ;
    float acc = 0.f;
    #pragma unroll 8
    for (int k = 0; k < KK; k++) {
        float v = yb[(size_t)k * HWSZ + hw];
        bool in = (h >= ai[k] - 8) && (h < ai[k] + 8) && (w >= aj[k] - 8) && (w < aj[k] + 8);
        acc += in ? v : 0.f;
    }
    s[(size_t)b * HWSZ + hw] = acc;

    sm[threadIdx.x] = acc;
    __syncthreads();
    for (int st = 128; st > 0; st >>= 1) {
        if (threadIdx.x < st) sm[threadIdx.x] = fmaxf(sm[threadIdx.x], sm[threadIdx.x + st]);
        __syncthreads();
    }
    if (threadIdx.x == 0) {
        union { float f; unsigned int i; } x; x.f = sm[0];
        atomicMax(&umax[b], x.i);
    }
}

// ---------------------------------------------------------------------------
// deconv body (bid in [0, BB*CC)); carves 48KB from smem.
// ---------------------------------------------------------------------------
template <int HEADS>
__device__ __forceinline__ void deconv_body(int bid, char* smem,
                                            const float* __restrict__ l1,
                                            const float* __restrict__ l2,
                                            const float* __restrict__ w2a,
                                            const float* __restrict__ w3a,
                                            const float* __restrict__ w2b,
                                            const float* __restrict__ w3b,
                                            unsigned short* __restrict__ outA,
                                            unsigned short* __restrict__ outB) {
    float (*L1)[64][64] = (float (*)[64][64])smem;
    float (*L2)[32][32] = (float (*)[32][32])(smem + 32768);

    const int tid = threadIdx.x;
    const int g   = bid & 255;
    const int b   = bid >> 8;

    const float4* l1b = (const float4*)(l1 + ((size_t)b * 2 * CC + 2 * g) * 4096);
    float4* L1p = (float4*)&L1[0][0][0];
    #pragma unroll
    for (int i = 0; i < 8; i++) L1p[tid + i * 256] = l1b[tid + i * 256];
    const float4* l2b = (const float4*)(l2 + ((size_t)b * 4 * CC + 4 * g) * 1024);
    float4* L2p = (float4*)&L2[0][0][0];
    #pragma unroll
    for (int i = 0; i < 4; i++) L2p[tid + i * 256] = l2b[tid + i * 256];

    const int x    = tid & 127;
    const int ytop = tid >> 7;

    const int pxo = x & 1, pyo = ytop & 1;
    const int mx0 = (x + pxo - 2) >> 1;
    const int dy2 = (ytop + pyo - 2) >> 1;
    const bool nok0 = (unsigned)mx0 < 64u;
    const bool nok1 = (unsigned)(mx0 + 1) < 64u;
    const int nc0 = mx0 & 63, nc1 = (mx0 + 1) & 63;

    const int px3 = (5 - (x & 3)) & 3;
    const int n30 = (x + px3 - 5) >> 2;
    const bool n3ok0 = (unsigned)n30 < 32u;
    const bool n3ok1 = (unsigned)(n30 + 1) < 32u;
    const int n3c0 = n30 & 31, n3c1 = (n30 + 1) & 31;
    int dy3[2], py3v[2];
    #pragma unroll
    for (int ph = 0; ph < 2; ph++) {
        int py3 = (5 - ((ytop + 2 * ph) & 3)) & 3;
        py3v[ph] = py3;
        dy3[ph] = (2 * ph + ytop + py3 - 5) >> 2;
    }

    __syncthreads();

    const float* w2s[2] = {w2a, w2b};
    const float* w3s[2] = {w3a, w3b};
    unsigned short* outs[2] = {outA, outB};

    #pragma unroll 1
    for (int hd = 0; hd < HEADS; ++hd) {
        const float* w2g = w2s[hd] + (size_t)g * 32;
        const float* w3g = w3s[hd] + (size_t)g * 256;

        float W2[2][2][2];
        #pragma unroll
        for (int ci = 0; ci < 2; ci++)
            #pragma unroll
            for (int a = 0; a < 2; a++)
                #pragma unroll
                for (int c = 0; c < 2; c++)
                    W2[ci][a][c] = w2g[ci * 16 + (pyo + 2 * a) * 4 + (pxo + 2 * c)];
        float W3[2][4][2][2];
        #pragma unroll
        for (int ph = 0; ph < 2; ph++)
            #pragma unroll
            for (int ci = 0; ci < 4; ci++)
                #pragma unroll
                for (int a = 0; a < 2; a++)
                    #pragma unroll
                    for (int c = 0; c < 2; c++)
                        W3[ph][ci][a][c] = w3g[ci * 64 + (py3v[ph] + 4 * a) * 8 + (px3 + 4 * c)];

        unsigned short* outb = outs[hd] + ((size_t)b * CC + g) * HWSZ;

        #pragma unroll 2
        for (int ii = 0; ii < 32; ++ii) {
            #pragma unroll
            for (int ph = 0; ph < 2; ph++) {
                const int i = 2 * ii + ph;
                float acc = 0.f;
                {
                    const int m0 = i + dy2;
                    #pragma unroll
                    for (int a = 0; a < 2; a++) {
                        int m = m0 + a;
                        bool mok = (unsigned)m < 64u;
                        int mc = m & 63;
                        #pragma unroll
                        for (int ci = 0; ci < 2; ci++) {
                            float v0 = (mok && nok0) ? L1[ci][mc][nc0] : 0.f;
                            float v1 = (mok && nok1) ? L1[ci][mc][nc1] : 0.f;
                            acc = fmaf(W2[ci][a][0], v0, acc);
                            acc = fmaf(W2[ci][a][1], v1, acc);
                        }
                    }
                }
                {
                    const int m0 = ii + dy3[ph];
                    #pragma unroll
                    for (int a = 0; a < 2; a++) {
                        int m = m0 + a;
                        bool mok = (unsigned)m < 32u;
                        int mc = m & 31;
                        #pragma unroll
                        for (int ci = 0; ci < 4; ci++) {
                            float v0 = (mok && n3ok0) ? L2[ci][mc][n3c0] : 0.f;
                            float v1 = (mok && n3ok1) ? L2[ci][mc][n3c1] : 0.f;
                            acc = fmaf(W3[ph][ci][a][0], v0, acc);
                            acc = fmaf(W3[ph][ci][a][1], v1, acc);
                        }
                    }
                }
                outb[(size_t)i * 256 + tid] = f2b(acc);
            }
        }
    }
}

// standalone kernels (fallback path)
__global__ __launch_bounds__(256) void smap_kernel(const float* __restrict__ y,
                                                   const unsigned long long* __restrict__ ymax,
                                                   float* __restrict__ s,
                                                   unsigned int* __restrict__ umax) {
    __shared__ __align__(16) char smem[1536];
    smap_body(blockIdx.x, smem, y, ymax, s, umax);
}
template <int HEADS>
__global__ __launch_bounds__(256) void deconv_kernel(const float* __restrict__ l1,
                                                     const float* __restrict__ l2,
                                                     const float* __restrict__ w2a,
                                                     const float* __restrict__ w3a,
                                                     const float* __restrict__ w2b,
                                                     const float* __restrict__ w3b,
                                                     unsigned short* __restrict__ outA,
                                                     unsigned short* __restrict__ outB) {
    __shared__ __align__(16) char smem[49152];
    deconv_body<HEADS>(blockIdx.x, smem, l1, l2, w2a, w3a, w2b, w3b, outA, outB);
}

// fused smap || dual-deconv: blocks [0,128) smap, [128, 640) deconv
__global__ __launch_bounds__(256) void smapdeconv_kernel(
    const float* __restrict__ y, const unsigned long long* __restrict__ ymax,
    float* __restrict__ s, unsigned int* __restrict__ umax,
    const float* __restrict__ l1, const float* __restrict__ l2,
    const float* __restrict__ w2a, const float* __restrict__ w3a,
    const float* __restrict__ w2b, const float* __restrict__ w3b,
    unsigned short* __restrict__ outA, unsigned short* __restrict__ outB)
{
    __shared__ __align__(16) char smem[49152];
    const int bid = blockIdx.x;
    if (bid < 128) smap_body(bid, smem, y, ymax, s, umax);
    else           deconv_body<2>(bid - 128, smem, l1, l2, w2a, w3a, w2b, w3b, outA, outB);
}

// ---------------------------------------------------------------------------
// BIG conv core (round-15 dbuf body).
// ---------------------------------------------------------------------------
template <int ADDB, int MULF>
__device__ __forceinline__ void conv_mfma_body(
    int y0, int co0, int b,
    const unsigned short* __restrict__ in,
    const unsigned short* __restrict__ wt,
    const float* __restrict__ bias,
    const unsigned short* __restrict__ addb,
    const float* __restrict__ xf,
    unsigned short* __restrict__ out,
    unsigned short (*Alds)[3 * 130 * 32])
{
    const int tid  = threadIdx.x;
    const int lane = tid & 63;
    const int wv   = tid >> 6;
    const int wco  = wv >> 1;
    const int wpx  = wv & 1;
    const int l15  = lane & 15;
    const int kg   = lane >> 4;

    const unsigned short* inb = in + (size_t)b * HWSZ * CC;
    const float* xfb = MULF ? (xf + (size_t)b * HWSZ) : nullptr;
    const unsigned short* wp = wt + (size_t)kg * 2048 + (size_t)(co0 + wco * 64 + l15) * 8;

    int ach[3][4];
    #pragma unroll
    for (int tl = 0; tl < 3; tl++)
        #pragma unroll
        for (int f = 0; f < 4; f++) {
            int px = wpx * 64 + f * 16 + l15 + tl;
            ach[tl][f] = (px * 4 + (kg ^ ((px >> 1) & 3))) * 8;
        }

    f32x4_t acc[4][4];
    #pragma unroll
    for (int i = 0; i < 4; i++)
        #pragma unroll
        for (int j = 0; j < 4; j++)
            acc[i][j] = (f32x4_t){0.f, 0.f, 0.f, 0.f};

    if (tid < 48) {
        int q4 = tid & 3;
        int hp = (tid >> 2) & 1;
        int r  = (tid >> 3) % 3;
        int bi = tid / 24;
        int px = hp ? 129 : 0;
        int chunk = (r * 130 + px) * 4 + (q4 ^ ((px >> 1) & 3));
        *reinterpret_cast<uint4*>(&Alds[bi][chunk * 8]) = make_uint4(0u, 0u, 0u, 0u);
    }

    uint4 streg[6];
    float sxf[6];

    auto load_A = [&](int cb) {
        #pragma unroll
        for (int i = 0; i < 6; i++) {
            int q   = tid + i * 256;
            int q4  = q & 3;
            int pxi = (q >> 2) & 127;
            int r   = q >> 9;
            int gy  = y0 - 1 + r;
            uint4 v = make_uint4(0u, 0u, 0u, 0u);
            float fxv = 0.f;
            if ((unsigned)gy < 128u) {
                v = *reinterpret_cast<const uint4*>(
                        inb + ((size_t)(gy * 128 + pxi)) * CC + cb * 32 + q4 * 8);
                if (MULF) fxv = xfb[gy * 128 + pxi];
            }
            streg[i] = v;
            if (MULF) sxf[i] = fxv;
        }
    };
    auto write_A = [&](int bufi) {
        #pragma unroll
        for (int i = 0; i < 6; i++) {
            int q   = tid + i * 256;
            int q4  = q & 3;
            int pxi = (q >> 2) & 127;
            int r   = q >> 9;
            int px  = pxi + 1;
            int chunk = (r * 130 + px) * 4 + (q4 ^ ((px >> 1) & 3));
            uint4 v = streg[i];
            if (MULF) {
                union { unsigned short u[8]; uint4 w; } pk;
                pk.w = v;
                float fm = sxf[i];
                #pragma unroll
                for (int e = 0; e < 8; e++) pk.u[e] = f2b(b2f(pk.u[e]) * fm);
                v = pk.w;
            }
            *reinterpret_cast<uint4*>(&Alds[bufi][chunk * 8]) = v;
        }
    };

    load_A(0);
    write_A(0);

    bf16x8_t W[3][4], P[2][4];
    #pragma unroll
    for (int f = 0; f < 4; f++) W[0][f] = *reinterpret_cast<const bf16x8_t*>(wp + f * 128);
    #pragma unroll
    for (int f = 0; f < 4; f++) W[1][f] = *reinterpret_cast<const bf16x8_t*>(wp + 8192 + f * 128);

    __syncthreads();
    #pragma unroll
    for (int f = 0; f < 4; f++)
        P[0][f] = *reinterpret_cast<const bf16x8_t*>(&Alds[0][ach[0][f]]);

    for (int cb = 0; cb < 8; ++cb) {
        const int bufi = cb & 1;
        if (cb + 1 < 8) load_A(cb + 1);
        const unsigned short* wcb = wp + (size_t)cb * 73728;
        #pragma unroll
        for (int t = 0; t < 9; ++t) {
            if (cb < 7 || t < 7) {
                #pragma unroll
                for (int f = 0; f < 4; f++)
                    W[(t + 2) % 3][f] = *reinterpret_cast<const bf16x8_t*>(
                        wcb + (t + 2) * 8192 + f * 128);
            }
            if (t < 8) {
                const int aoff = ((t + 1) / 3) * 4160;
                #pragma unroll
                for (int f = 0; f < 4; f++)
                    P[(t + 1) & 1][f] = *reinterpret_cast<const bf16x8_t*>(
                        &Alds[bufi][aoff + ach[(t + 1) % 3][f]]);
            }
            __builtin_amdgcn_sched_barrier(0);
            #pragma unroll
            for (int cf = 0; cf < 4; cf++)
                #pragma unroll
                for (int pf = 0; pf < 4; pf++)
                    acc[cf][pf] = __builtin_amdgcn_mfma_f32_16x16x32_bf16(
                        W[t % 3][cf], P[t & 1][pf], acc[cf][pf], 0, 0, 0);
        }
        if (cb + 1 < 8) write_A(bufi ^ 1);
        __syncthreads();
        if (cb + 1 < 8) {
            #pragma unroll
            for (int f = 0; f < 4; f++)
                P[0][f] = *reinterpret_cast<const bf16x8_t*>(&Alds[(cb + 1) & 1][ach[0][f]]);
        }
    }

    size_t outB = ((size_t)b * HWSZ + (size_t)y0 * 128) * CC;
    #pragma unroll
    for (int cf = 0; cf < 4; cf++) {
        int co = co0 + wco * 64 + cf * 16 + kg * 4;
        float bs0 = bias[co], bs1 = bias[co + 1], bs2 = bias[co + 2], bs3 = bias[co + 3];
        #pragma unroll
        for (int pf = 0; pf < 4; pf++) {
            int x = wpx * 64 + pf * 16 + l15;
            float v0 = silu_f(acc[cf][pf][0] + bs0);
            float v1 = silu_f(acc[cf][pf][1] + bs1);
            float v2 = silu_f(acc[cf][pf][2] + bs2);
            float v3 = silu_f(acc[cf][pf][3] + bs3);
            if (ADDB) {
                size_t ab = ((size_t)b * CC + co) * HWSZ + (size_t)y0 * 128 + x;
                v0 += b2f(addb[ab]);
                v1 += b2f(addb[ab + HWSZ]);
                v2 += b2f(addb[ab + 2 * HWSZ]);
                v3 += b2f(addb[ab + 3 * HWSZ]);
            }
            union { unsigned short u[4]; uint2 v; } pk;
            pk.u[0] = f2b(v0); pk.u[1] = f2b(v1); pk.u[2] = f2b(v2); pk.u[3] = f2b(v3);
            *reinterpret_cast<uint2*>(&out[outB + (size_t)x * CC + co]) = pk.v;
        }
    }
}

// single-head conv (grid 512)
template <int ADDB, int MULF>
__global__ __launch_bounds__(256, 2) void conv_mfma_kernel(
    const unsigned short* __restrict__ in,
    const unsigned short* __restrict__ wt,
    const float* __restrict__ bias,
    const unsigned short* __restrict__ addb,
    const float* __restrict__ xf,
    unsigned short* __restrict__ out)
{
    __shared__ __align__(16) unsigned short Alds[2][3 * 130 * 32];
    const int l   = (blockIdx.x & 7) * 64 + (blockIdx.x >> 3);
    const int y0  = l >> 2;
    const int co0 = ((l >> 1) & 1) * 128;
    const int b   = l & 1;
    conv_mfma_body<ADDB, MULF>(y0, co0, b, in, wt, bias, addb, xf, out, Alds);
}

// ---------------------------------------------------------------------------
// c1a body: conv 1->256 (input = s / max), + bias, silu -> bf16 NHWC.
// Carves ~9.6KB from smem. bid in [0,1024).
// ---------------------------------------------------------------------------
__device__ __forceinline__ void c1a_body(int bid, char* smem,
                                         const float* __restrict__ s,
                                         const unsigned int* __restrict__ umax,
                                         const float* __restrict__ w,
                                         const float* __restrict__ bias,
                                         unsigned short* __restrict__ out) {
    float* W = (float*)smem;                 // 2304 floats
    float (*S)[34] = (float (*)[34])(smem + 2304 * 4);   // 3x34 floats

    const int tid = threadIdx.x;
    const int b   = bid >> 9;
    const int seg = bid & 511;
    const int y   = seg >> 2;
    const int x0  = (seg & 3) * 32;

    for (int i = tid; i < 2304; i += 256) W[i] = w[i];
    if (tid < 102) {
        int r = tid / 34, xx = tid - r * 34;
        int gy = y - 1 + r, gx = x0 - 1 + xx;
        S[r][xx] = ((unsigned)gy < 128u && (unsigned)gx < 128u)
                       ? s[(size_t)b * HWSZ + gy * 128 + gx] : 0.f;
    }
    __syncthreads();

    const float im = 1.f / u2f(umax[b]);
    const int cog = tid >> 5;
    const int px  = tid & 31;

    float sv[9];
    #pragma unroll
    for (int r = 0; r < 3; r++)
        #pragma unroll
        for (int d = 0; d < 3; d++)
            sv[r * 3 + d] = S[r][px + d];

    unsigned short* op =
        &out[((size_t)b * HWSZ + (size_t)y * 128 + x0 + px) * CC + cog * 32];
    #pragma unroll
    for (int q = 0; q < 4; q++) {
        union { unsigned short u[8]; uint4 v; } pk;
        #pragma unroll
        for (int j = 0; j < 8; j++) {
            int co = cog * 32 + q * 8 + j;
            float a = 0.f;
            #pragma unroll
            for (int t = 0; t < 9; t++) a = fmaf(W[co * 9 + t], sv[t], a);
            pk.u[j] = f2b(silu_f(a * im + bias[co]));
        }
        *reinterpret_cast<uint4*>(op + q * 8) = pk.v;
    }
}

// standalone c1a (fallback)
__global__ __launch_bounds__(256) void conv_c1a_kernel(const float* __restrict__ s,
                                                       const unsigned int* __restrict__ umax,
                                                       const float* __restrict__ w,
                                                       const float* __restrict__ bias,
                                                       unsigned short* __restrict__ out) {
    __shared__ __align__(16) char smem[9728];
    c1a_body(blockIdx.x, smem, s, umax, w, bias, out);
}

// dual-head p1 conv + parallel c1a: blocks [0,1024) dual-p1, [1024,2048) c1a.
__global__ __launch_bounds__(256, 2) void dualp1_c1a_kernel(
    const unsigned short* __restrict__ in,
    const unsigned short* __restrict__ wt2set,
    const float* __restrict__ biasB,
    const float* __restrict__ biasH,
    const unsigned short* __restrict__ addbB,
    const unsigned short* __restrict__ addbH,
    unsigned short* __restrict__ outB,
    unsigned short* __restrict__ outH,
    const float* __restrict__ s,
    const unsigned int* __restrict__ umax,
    const float* __restrict__ c1aw,
    const float* __restrict__ c1ab,
    unsigned short* __restrict__ t1out)
{
    __shared__ __align__(16) char smem[2 * 3 * 130 * 32 * 2];   // 49920 B
    const int bid = blockIdx.x;
    if (bid < 1024) {
        const int l    = (bid & 7) * 128 + (bid >> 3);
        const int y0   = l >> 3;
        const int c3   = l & 7;
        const int head = c3 >> 2;
        const int co0  = ((c3 >> 1) & 1) * 128;
        const int b    = c3 & 1;
        conv_mfma_body<1, 0>(y0, co0, b, in, wt2set + (size_t)head * WTSZ,
                             head ? biasH : biasB, head ? addbH : addbB,
                             nullptr, head ? outH : outB,
                             (unsigned short (*)[3 * 130 * 32])smem);
    } else {
        c1a_body(bid - 1024, smem, s, umax, c1aw, c1ab, t1out);
    }
}

// dual-head p1 conv (fallback-compat, grid 1024)
__global__ __launch_bounds__(256, 2) void conv_mfma_dual_kernel(
    const unsigned short* __restrict__ in,
    const unsigned short* __restrict__ wt2set,
    const float* __restrict__ biasB,
    const float* __restrict__ biasH,
    const unsigned short* __restrict__ addbB,
    const unsigned short* __restrict__ addbH,
    unsigned short* __restrict__ outB,
    unsigned short* __restrict__ outH)
{
    __shared__ __align__(16) unsigned short Alds[2][3 * 130 * 32];
    const int l    = (blockIdx.x & 7) * 128 + (blockIdx.x >> 3);
    const int y0   = l >> 3;
    const int c3   = l & 7;
    const int head = c3 >> 2;
    const int co0  = ((c3 >> 1) & 1) * 128;
    const int b    = c3 & 1;
    conv_mfma_body<1, 0>(y0, co0, b, in, wt2set + (size_t)head * WTSZ,
                         head ? biasH : biasB, head ? addbH : addbB,
                         nullptr, head ? outH : outB, Alds);
}

// dual-mix (grid 1024): head 0 = xb, head 1 = t2 (MULF)
__global__ __launch_bounds__(256, 2) void conv_mfma_dualmix_kernel(
    const unsigned short* __restrict__ in0,
    const unsigned short* __restrict__ in1,
    const unsigned short* __restrict__ wt0,
    const unsigned short* __restrict__ wt1,
    const float* __restrict__ bias0,
    const float* __restrict__ bias1,
    const float* __restrict__ xf,
    unsigned short* __restrict__ out0,
    unsigned short* __restrict__ out1)
{
    __shared__ __align__(16) unsigned short Alds[2][3 * 130 * 32];
    const int l    = (blockIdx.x & 7) * 128 + (blockIdx.x >> 3);
    const int y0   = l >> 3;
    const int c3   = l & 7;
    const int head = c3 >> 2;
    const int co0  = ((c3 >> 1) & 1) * 128;
    const int b    = c3 & 1;
    if (head == 0)
        conv_mfma_body<0, 0>(y0, co0, b, in0, wt0, bias0, nullptr, nullptr, out0, Alds);
    else
        conv_mfma_body<0, 1>(y0, co0, b, in1, wt1, bias1, nullptr, xf, out1, Alds);
}

// ---------------------------------------------------------------------------
// Small conv body: 256 -> COUT, NHWC bf16 input; WL = smem float region.
// ---------------------------------------------------------------------------
template <int COUT, int MODE>
__device__ __forceinline__ void small_conv_body(int bid, float* WL,
                                                const unsigned short* __restrict__ in,
                                                const float* __restrict__ w,
                                                const float* __restrict__ bias,
                                                float* __restrict__ out)
{
    const int tid = threadIdx.x;
    for (int i = tid; i < COUT * 2304; i += 256) {
        int e = i & 7;
        int g = (i >> 3) & 31;
        int rest = i >> 8;
        int t = rest % 9;
        int co = rest / 9;
        WL[((co * 9 + t) * 32 + g) * 12 + e] = w[((size_t)co * 256 + g * 8 + e) * 9 + t];
    }
    __syncthreads();

    const int lane = tid & 63;
    const int wv   = tid >> 6;
    const int c32  = lane & 31;
    const int ps   = lane >> 5;
    const int grp  = bid * 4 + wv;
    const int base = grp * 4;
    const int b    = base >> 14;
    const int pix  = base & (HWSZ - 1);
    const int y    = pix >> 7;
    const int x0   = pix & 127;
    const int p0x  = x0 + 2 * ps;

    const unsigned short* inb = in + (size_t)b * HWSZ * CC;

    uint4 d[3][4];
    #pragma unroll
    for (int r = 0; r < 3; r++) {
        int gy = y - 1 + r;
        #pragma unroll
        for (int cx = 0; cx < 4; cx++) {
            int gx = p0x - 1 + cx;
            uint4 v = make_uint4(0u, 0u, 0u, 0u);
            if ((unsigned)gy < 128u && (unsigned)gx < 128u)
                v = *reinterpret_cast<const uint4*>(
                        inb + ((size_t)(gy * 128 + gx)) * CC + c32 * 8);
            d[r][cx] = v;
        }
    }

    float acc[2][COUT];
    #pragma unroll
    for (int p = 0; p < 2; p++)
        #pragma unroll
        for (int c = 0; c < COUT; c++) acc[p][c] = 0.f;

    #pragma unroll
    for (int r = 0; r < 3; r++) {
        float f[4][8];
        #pragma unroll
        for (int cx = 0; cx < 4; cx++) {
            union { unsigned short u[8]; uint4 v; } pk;
            pk.v = d[r][cx];
            #pragma unroll
            for (int e = 0; e < 8; e++) f[cx][e] = b2f(pk.u[e]);
        }
        #pragma unroll
        for (int dx = 0; dx < 3; dx++) {
            #pragma unroll
            for (int co = 0; co < COUT; co++) {
                int bse = ((co * 9 + r * 3 + dx) * 32 + c32) * 12;
                float4 wa = *(const float4*)&WL[bse];
                float4 wb = *(const float4*)&WL[bse + 4];
                #pragma unroll
                for (int p = 0; p < 2; p++) {
                    const float* ff = f[dx + p];
                    float a = acc[p][co];
                    a = fmaf(ff[0], wa.x, a); a = fmaf(ff[1], wa.y, a);
                    a = fmaf(ff[2], wa.z, a); a = fmaf(ff[3], wa.w, a);
                    a = fmaf(ff[4], wb.x, a); a = fmaf(ff[5], wb.y, a);
                    a = fmaf(ff[6], wb.z, a); a = fmaf(ff[7], wb.w, a);
                    acc[p][co] = a;
                }
            }
        }
    }

    #pragma unroll
    for (int m = 1; m <= 16; m <<= 1)
        #pragma unroll
        for (int p = 0; p < 2; p++)
            #pragma unroll
            for (int co = 0; co < COUT; co++)
                acc[p][co] += __shfl_xor(acc[p][co], m);

    if (c32 == 0) {
        #pragma unroll
        for (int p = 0; p < 2; p++) {
            size_t pixidx = (size_t)base + 2 * ps + p;
            if (MODE == 0) {
                ((float4*)out)[pixidx] = make_float4(
                    acc[p][0] + bias[0],
                    acc[p][COUT > 1 ? 1 : 0] + bias[COUT > 1 ? 1 : 0],
                    acc[p][COUT > 2 ? 2 : 0] + bias[COUT > 2 ? 2 : 0],
                    acc[p][COUT > 3 ? 3 : 0] + bias[COUT > 3 ? 3 : 0]);
            } else if (MODE == 1) {
                out[pixidx] = acc[p][0] + bias[0];
            } else {
                out[pixidx] = sigm_f(acc[p][0] + bias[0]);
            }
        }
    }
}

template <int COUT, int MODE>
__global__ __launch_bounds__(256) void small_conv_kernel(
    const unsigned short* __restrict__ in,
    const float* __restrict__ w,
    const float* __restrict__ bias,
    float* __restrict__ out)
{
    __shared__ float WL[COUT * 9 * 32 * 12];
    small_conv_body<COUT, MODE>(blockIdx.x, WL, in, w, bias, out);
}

// fused t3 || c2box: blocks [0,512) t3 conv, [512, 2560) small_conv<4,0>
__global__ __launch_bounds__(256, 2) void t3c2_kernel(
    const unsigned short* __restrict__ t2in,     // bufA
    const unsigned short* __restrict__ wt4,      // h_c2b set
    const float* __restrict__ biasT3,
    unsigned short* __restrict__ t3out,          // bufB
    const unsigned short* __restrict__ xbin,     // bufD
    const float* __restrict__ c2w,
    const float* __restrict__ c2b,
    float* __restrict__ boxout)
{
    __shared__ __align__(16) char smem[55296];
    const int bid = blockIdx.x;
    if (bid < 512) {
        const int l   = (bid & 7) * 64 + (bid >> 3);
        const int y0  = l >> 2;
        const int co0 = ((l >> 1) & 1) * 128;
        const int b   = l & 1;
        conv_mfma_body<0, 0>(y0, co0, b, t2in, wt4, biasT3, nullptr, nullptr, t3out,
                             (unsigned short (*)[3 * 130 * 32])smem);
    } else {
        small_conv_body<4, 0>(bid - 512, (float*)smem, xbin, c2w, c2b, boxout);
    }
}

// ---------------------------------------------------------------------------
extern "C" void kernel_launch(void* const* d_in, const int* in_sizes, int n_in,
                              void* d_out, int out_size, void* d_ws, size_t ws_size,
                              hipStream_t stream) {
    const float* emb    = (const float*)d_in[0];
    const float* trk    = (const float*)d_in[1];
    const float* l0     = (const float*)d_in[2];
    const float* l1     = (const float*)d_in[3];
    const float* l2     = (const float*)d_in[4];
    const float* b_p1w  = (const float*)d_in[5];
    const float* b_p1b  = (const float*)d_in[6];
    const float* b_p2w  = (const float*)d_in[7];
    const float* b_p3w  = (const float*)d_in[8];
    const float* b_c1w  = (const float*)d_in[9];
    const float* b_c1b  = (const float*)d_in[10];
    const float* b_c2w  = (const float*)d_in[11];
    const float* b_c2b  = (const float*)d_in[12];
    const float* h_p1w  = (const float*)d_in[13];
    const float* h_p1b  = (const float*)d_in[14];
    const float* h_p2w  = (const float*)d_in[15];
    const float* h_p3w  = (const float*)d_in[16];
    const float* h_c1aw = (const float*)d_in[17];
    const float* h_c1ab = (const float*)d_in[18];
    const float* h_c1bw = (const float*)d_in[19];
    const float* h_c1bb = (const float*)d_in[20];
    const float* h_c2aw = (const float*)d_in[21];
    const float* h_c2ab = (const float*)d_in[22];
    const float* h_c2bw = (const float*)d_in[23];
    const float* h_c2bb = (const float*)d_in[24];
    const float* h_c2cw = (const float*)d_in[25];
    const float* h_c2cb = (const float*)d_in[26];

    float* outp = (float*)d_out;   // [0,32768): hmmap ; [32768,163840): siambox NHWC

    const size_t ACT = (size_t)BB * CC * HWSZ;   // 8,388,608 elems
    const size_t WT  = (size_t)WTSZ;             // 589,824 elems
    const size_t SMALLS = 132096;                // ushort units for small fp32 region

    unsigned short* l0nh = (unsigned short*)d_ws;
    unsigned short* wtP  = l0nh + ACT;           // set0=b_p1, 1=h_p1, 2=b_c1, 3=h_c2a, 4=h_c2b
    unsigned short* bufA = wtP + 5 * WT;
    unsigned short* bufB = bufA + ACT;
    unsigned short* bufC = bufB + ACT;
    float* sbuf   = (float*)(bufC + ACT);
    float* xfb    = sbuf + (size_t)BB * HWSZ;
    unsigned long long* ymax = (unsigned long long*)(xfb + (size_t)BB * HWSZ);
    unsigned int* umax = (unsigned int*)(ymax + BB * KK);
    unsigned short* bufD = bufC + ACT + SMALLS;  // fast-path only
    unsigned short* bufE = bufD + ACT;           // fast-path only (t1)
    float* ybuf   = (float*)bufB;                // alias: y consumed before bufB reused

    const size_t NEED = (size_t)(bufE + ACT - l0nh) * sizeof(unsigned short);
    const bool fast = ws_size >= NEED;

    // L1: fused preps (cvt + 5x wprep); cvt block 0 inits ymax/umax
    prep_fused_kernel<<<256 + 11520, 256, 0, stream>>>(
        l0, l0nh, ymax, umax, b_p1w, h_p1w, b_c1w, h_c2aw, h_c2bw, wtP);

    // L2: correlation + fused argmax
    ycorr_kernel<<<dim3(256, BB), 256, 0, stream>>>(emb, trk, ybuf, ymax);

    if (fast) {
        // L3: smap || dual deconv (box->bufA, hm->bufD)
        smapdeconv_kernel<<<128 + 512, 256, 0, stream>>>(
            ybuf, ymax, sbuf, umax,
            l1, l2, b_p2w, b_p3w, h_p2w, h_p3w, bufA, bufD);
        // L4: dual p1 (xd_box->bufB, xd_hm->bufC) || c1a (t1 -> bufE)
        dualp1_c1a_kernel<<<1024 + 1024, 256, 0, stream>>>(
            l0nh, wtP, b_p1b, h_p1b, bufA, bufD, bufB, bufC,
            sbuf, umax, h_c1aw, h_c1ab, bufE);
        // L5: xf (bufE -> xfb)
        small_conv_kernel<1, 1><<<2048, 256, 0, stream>>>(bufE, h_c1bw, h_c1bb, xfb);
        // L6: dual mix: xb (bufB->bufD) || t2 (bufC * xf -> bufA)
        conv_mfma_dualmix_kernel<<<1024, 256, 0, stream>>>(bufB, bufC,
                                                           wtP + 2 * WT, wtP + 3 * WT,
                                                           b_c1b, h_c2ab, xfb,
                                                           bufD, bufA);
        // L7: t3 (bufA->bufB) || c2box (bufD->out)
        t3c2_kernel<<<512 + 2048, 256, 0, stream>>>(bufA, wtP + 4 * WT, h_c2bb, bufB,
                                                    bufD, b_c2w, b_c2b,
                                                    outp + BB * HWSZ);
        // L8: hmmap (bufB -> out)
        small_conv_kernel<1, 2><<<2048, 256, 0, stream>>>(bufB, h_c2cw, h_c2cb, outp);
    } else {
        // fallback schedule (Db=bufA, X1=bufB, X2=bufC), all singles
        smap_kernel<<<64 * BB, 256, 0, stream>>>(ybuf, ymax, sbuf, umax);
        deconv_kernel<1><<<BB * CC, 256, 0, stream>>>(l1, l2, b_p2w, b_p3w,
                                                      nullptr, nullptr, bufA, nullptr);
        conv_mfma_kernel<1, 0><<<512, 256, 0, stream>>>(l0nh, wtP, b_p1b, bufA,
                                                        nullptr, bufB);                 // xd_box
        conv_mfma_kernel<0, 0><<<512, 256, 0, stream>>>(bufB, wtP + 2 * WT, b_c1b,
                                                        nullptr, nullptr, bufC);        // xb
        small_conv_kernel<4, 0><<<2048, 256, 0, stream>>>(bufC, b_c2w, b_c2b,
                                                          outp + BB * HWSZ);
        deconv_kernel<1><<<BB * CC, 256, 0, stream>>>(l1, l2, h_p2w, h_p3w,
                                                      nullptr, nullptr, bufA, nullptr);
        conv_mfma_kernel<1, 0><<<512, 256, 0, stream>>>(l0nh, wtP + 1 * WT, h_p1b, bufA,
                                                        nullptr, bufB);                 // xd_hm
        conv_c1a_kernel<<<1024, 256, 0, stream>>>(sbuf, umax, h_c1aw, h_c1ab, bufC);    // t1
        small_conv_kernel<1, 1><<<2048, 256, 0, stream>>>(bufC, h_c1bw, h_c1bb, xfb);   // xf
        conv_mfma_kernel<0, 1><<<512, 256, 0, stream>>>(bufB, wtP + 3 * WT, h_c2ab,
                                                        nullptr, xfb, bufA);            // t2
        conv_mfma_kernel<0, 0><<<512, 256, 0, stream>>>(bufA, wtP + 4 * WT, h_c2bb,
                                                        nullptr, nullptr, bufC);        // t3
        small_conv_kernel<1, 2><<<2048, 256, 0, stream>>>(bufC, h_c2cw, h_c2cb, outp);  // hmmap
    }
}